// Round 2
// baseline (2118.276 us; speedup 1.0000x reference)
//
#include <hip/hip_runtime.h>
#include <hip/hip_bf16.h>
#include <hip/hip_fp16.h>

// SVD-RNN: W = U diag(s) V from Householder chains; h_t = tanh(xp_t + W h_{t-1});
// out_t = h_t W_out^T + b_out.
#define BB 64
#define TT 2048
#define II 128
#define HH 256
#define OO 128
#define RCH 8                      // recurrence chunk length (global I/O batching)

typedef _Float16 f16x2 __attribute__((ext_vector_type(2)));
typedef _Float16 f16x8 __attribute__((ext_vector_type(8)));
typedef float f32x4 __attribute__((ext_vector_type(4)));

#if __has_builtin(__builtin_amdgcn_fdot2)
__device__ __forceinline__ float fdot2(f16x2 a, f16x2 b, float c) {
    return __builtin_amdgcn_fdot2(a, b, c, false);
}
#else
__device__ __forceinline__ float fdot2(f16x2 a, f16x2 b, float c) {
    return fmaf((float)a.x, (float)b.x, fmaf((float)a.y, (float)b.y, c));
}
#endif

__device__ __forceinline__ f16x2 u2h(unsigned int u) { return __builtin_bit_cast(f16x2, u); }
__device__ __forceinline__ unsigned int packf16(float a, float b) {
    return __builtin_bit_cast(unsigned int, f16x2{(_Float16)a, (_Float16)b});
}

__device__ __forceinline__ float tanh_fast(float x) {
    float xc = fminf(fmaxf(x, -9.0f), 9.0f);
    float e = __expf(2.0f * xc);
    return (e - 1.0f) * __fdividef(1.0f, e + 1.0f);
}

// lgkm-only workgroup barrier: orders LDS writes/reads across waves WITHOUT
// draining vmcnt, so chunked global prefetch/stores stay in flight across
// steps (stock __syncthreads emits s_waitcnt vmcnt(0) expcnt(0) lgkmcnt(0)
// which would expose the xp-prefetch HBM latency once per chunk).
__device__ __forceinline__ void step_barrier() {
    __builtin_amdgcn_sched_barrier(0);
    asm volatile("s_waitcnt lgkmcnt(0)" ::: "memory");
    __builtin_amdgcn_s_barrier();
    __builtin_amdgcn_sched_barrier(0);
}

// ---------------------------------------------------------------------------
// Kernel 1: masked+flipped Householder vectors and betas.
// ---------------------------------------------------------------------------
__global__ __launch_bounds__(64) void prep_kernel(
    const float* __restrict__ u_raw, const float* __restrict__ v_raw,
    float* __restrict__ u_eff, float* __restrict__ v_eff,
    float* __restrict__ beta_u, float* __restrict__ beta_v)
{
    const int row = blockIdx.x;
    const int lane = threadIdx.x;
    const bool isU = row < HH;
    const int i = isU ? row : row - HH;
    const float* src = isU ? (u_raw + (size_t)i * HH) : (v_raw + (size_t)(HH - 1 - i) * HH);
    float* dst = (isU ? u_eff : v_eff) + (size_t)i * HH;
    const int lo = isU ? (HH - 1 - i) : i;
    float ss = 0.0f;
    for (int c = lane; c < HH; c += 64) {
        float vv = (c >= lo) ? src[HH - 1 - c] : 0.0f;
        dst[c] = vv;
        ss += vv * vv;
    }
    for (int m = 1; m < 64; m <<= 1) ss += __shfl_xor(ss, m, 64);
    if (lane == 0) (isU ? beta_u : beta_v)[i] = 2.0f / ss;
}

// ---------------------------------------------------------------------------
// Kernel 2: Householder chain per column.
// ---------------------------------------------------------------------------
__global__ __launch_bounds__(256) void hh_kernel(
    const float* __restrict__ u_eff, const float* __restrict__ v_eff,
    const float* __restrict__ beta_u, const float* __restrict__ beta_v,
    float* __restrict__ Ucol, float* __restrict__ Vrow)
{
    const int wid = blockIdx.x * 4 + (threadIdx.x >> 6);
    const int lane = threadIdx.x & 63;
    const bool isU = wid < HH;
    const int j = isU ? wid : wid - HH;
    const float* eff = isU ? u_eff : v_eff;
    const float* beta = isU ? beta_u : beta_v;

    float cr0 = (j == 4 * lane + 0) ? 1.0f : 0.0f;
    float cr1 = (j == 4 * lane + 1) ? 1.0f : 0.0f;
    float cr2 = (j == 4 * lane + 2) ? 1.0f : 0.0f;
    float cr3 = (j == 4 * lane + 3) ? 1.0f : 0.0f;

    const int i0 = isU ? (HH - 1 - j) : 0;
    for (int i = i0; i < HH; ++i) {
        const float4 v4 = *(const float4*)(eff + (size_t)i * HH + lane * 4);
        float d = v4.x * cr0 + v4.y * cr1 + v4.z * cr2 + v4.w * cr3;
        for (int m = 1; m < 64; m <<= 1) d += __shfl_xor(d, m, 64);
        const float t = beta[i] * d;
        cr0 = fmaf(-t, v4.x, cr0);
        cr1 = fmaf(-t, v4.y, cr1);
        cr2 = fmaf(-t, v4.z, cr2);
        cr3 = fmaf(-t, v4.w, cr3);
    }
    if (isU) {
        *(float4*)(Ucol + (size_t)j * HH + lane * 4) = make_float4(cr0, cr1, cr2, cr3);
    } else {
        Vrow[(size_t)(4 * lane + 0) * HH + j] = cr0;
        Vrow[(size_t)(4 * lane + 1) * HH + j] = cr1;
        Vrow[(size_t)(4 * lane + 2) * HH + j] = cr2;
        Vrow[(size_t)(4 * lane + 3) * HH + j] = cr3;
    }
}

// ---------------------------------------------------------------------------
// Kernel 3: W[r][c] = sum_k Ucol[k][r] * sig[k] * Vrow[k][c]
// ---------------------------------------------------------------------------
__global__ __launch_bounds__(256) void w_kernel(
    const float* __restrict__ Ucol, const float* __restrict__ Vrow,
    const float* __restrict__ sig, float* __restrict__ Wm)
{
    const int r = blockIdx.x;
    const int c = threadIdx.x;
    float acc = 0.0f;
    #pragma unroll 4
    for (int k = 0; k < HH; ++k) {
        acc = fmaf(Ucol[(size_t)k * HH + r] * sig[k], Vrow[(size_t)k * HH + c], acc);
    }
    Wm[(size_t)r * HH + c] = acc;
}

// ---------------------------------------------------------------------------
// MFMA tiled GEMM with bias: C[M][N] = A[M][K] * B[N][K]^T + bias[N].
// BM=128, BN=64, BK=32; 256 threads = 4 waves, each wave a 64x32 quadrant
// (4 m-tiles x 2 n-tiles of 16x16, mfma_f32_16x16x32_f16).
// ---------------------------------------------------------------------------
__device__ __forceinline__ void stage16(_Float16* dst, const float* src) {
    #pragma unroll
    for (int i = 0; i < 4; ++i) {
        float4 f = ((const float4*)src)[i];
        ((f16x2*)dst)[2 * i + 0] = f16x2{(_Float16)f.x, (_Float16)f.y};
        ((f16x2*)dst)[2 * i + 1] = f16x2{(_Float16)f.z, (_Float16)f.w};
    }
}
__device__ __forceinline__ void stage16(_Float16* dst, const __half* src) {
    ((uint4*)dst)[0] = ((const uint4*)src)[0];
    ((uint4*)dst)[1] = ((const uint4*)src)[1];
}
__device__ __forceinline__ void storeC(float* p, float v) { *p = v; }
__device__ __forceinline__ void storeC(__half* p, float v) { *p = __float2half_rn(v); }

template <typename AT, typename OT>
__global__ __launch_bounds__(256) void gemm_mfma(
    const AT* __restrict__ A, const float* __restrict__ Bm,
    const float* __restrict__ bias, OT* __restrict__ C,
    int M, int N, int K)
{
    __shared__ _Float16 As[128][40];
    __shared__ _Float16 Bs[64][40];
    const int tid = threadIdx.x;
    const int m0 = blockIdx.x * 128;
    const int n0 = blockIdx.y * 64;
    const int lane = tid & 63;
    const int w = tid >> 6;
    const int lo = lane & 15;
    const int qd = lane >> 4;
    const int mh = w >> 1;               // m-half (64 rows)
    const int nh = w & 1;                // n-half (32 cols)
    const int srow = tid >> 1;           // staging row 0..127
    const int shalf = tid & 1;           // 16-f16 half of the 32-k row

    f32x4 acc[4][2] = {};
    for (int k0 = 0; k0 < K; k0 += 32) {
        stage16(&As[srow][shalf * 16], A + (size_t)(m0 + srow) * K + k0 + shalf * 16);
        if (tid < 128)
            stage16(&Bs[srow][shalf * 16], Bm + (size_t)(n0 + srow) * K + k0 + shalf * 16);
        __syncthreads();
        f16x8 af[4], bf[2];
        #pragma unroll
        for (int mt = 0; mt < 4; ++mt)
            af[mt] = *(const f16x8*)&As[64 * mh + 16 * mt + lo][qd * 8];
        #pragma unroll
        for (int nt = 0; nt < 2; ++nt)
            bf[nt] = *(const f16x8*)&Bs[32 * nh + 16 * nt + lo][qd * 8];
        #pragma unroll
        for (int mt = 0; mt < 4; ++mt)
            #pragma unroll
            for (int nt = 0; nt < 2; ++nt)
                acc[mt][nt] = __builtin_amdgcn_mfma_f32_16x16x32_f16(
                    af[mt], bf[nt], acc[mt][nt], 0, 0, 0);
        __syncthreads();
    }
    #pragma unroll
    for (int nt = 0; nt < 2; ++nt) {
        const int n = n0 + 32 * nh + 16 * nt + lo;
        const float bv = bias[n];
        #pragma unroll
        for (int mt = 0; mt < 4; ++mt) {
            const int m = m0 + 64 * mh + 16 * mt + 4 * qd;
            #pragma unroll
            for (int r = 0; r < 4; ++r)
                storeC(C + (size_t)(m + r) * N + n, acc[mt][nt][r] + bv);
        }
    }
}

// ---------------------------------------------------------------------------
// Kernel 5: recurrence — TWO BATCHES PER WG (32 WGs x 512 threads).
// R1 post-mortem: row-split b128-broadcast variant was LDS-pipe-bound
// (128 ds_read_b128/CU/step ~= 1500 cy — matched the regression). The
// proven k-split structure has only ~430 cy/step of LDS-pipe time; its
// 1386 cy/step was dominated by the UNHIDDEN serial chain (2 barriers +
// 2 LDS round-trips + dot/tanh chains) since each CU held exactly one
// dependent recurrence. Fix: interleave TWO independent batches per WG.
// W fragment is shared (no reg duplication); phase-1 dots for A/B
// interleave in every wave (8 independent fdot2 chains); phase-2 for A
// runs on waves 0-1 IN PARALLEL with B on waves 2-3; both barriers and
// both LDS round-trip latencies amortize over 2 batch-steps. Barriers
// are lgkm-only so chunked xp/hall global traffic never drains in-loop.
// ---------------------------------------------------------------------------
__global__ __launch_bounds__(512) void recur_kernel(
    const float* __restrict__ Wm,              // [256][256] f32 row-major
    const __half* __restrict__ xp,             // [B][T][256] f16
    __half* __restrict__ hall)                 // [B][T][256] f16
{
    const int b0 = blockIdx.x * 2;
    const int tid = threadIdx.x;
    const int l = tid & 63;
    const int q = tid >> 6;        // wave 0..7

    __shared__ float ps[2][8][HH];                 // per-batch partial sums, 16 KB
    __shared__ unsigned int hbits[2][2][HH / 2];   // [batch][parity][128], 2 KB

    // W fragment: rows 4l..4l+3, cols q*32..q*32+32, as f16 pairs (64 VGPRs).
    f16x2 w2[4][16];
    #pragma unroll
    for (int r = 0; r < 4; ++r) {
        const float* Wp = Wm + (size_t)(4 * l + r) * HH + q * 32;
        #pragma unroll
        for (int c4 = 0; c4 < 8; ++c4) {
            float4 f = *(const float4*)(Wp + c4 * 4);
            w2[r][c4 * 2 + 0] = f16x2{(_Float16)f.x, (_Float16)f.y};
            w2[r][c4 * 2 + 1] = f16x2{(_Float16)f.z, (_Float16)f.w};
        }
    }
    if (tid < 256) hbits[tid >> 7][0][tid & 127] = 0u;
    __syncthreads();

    // Phase-2 / global-I/O role: tid<256; bb = batch (0/1), t2 = column pair.
    const int bb = tid >> 7;
    const int t2 = tid & 127;
    const unsigned int* xpw = (const unsigned int*)(xp + (size_t)(b0 + bb) * TT * HH);
    unsigned int* hw = (unsigned int*)(hall + (size_t)(b0 + bb) * TT * HH);

    unsigned int xpcur[RCH], xpnxt[RCH], hst[RCH];
    if (tid < 256) {
        #pragma unroll
        for (int s = 0; s < RCH; ++s) xpcur[s] = xpw[(size_t)s * 128 + t2];
    }

    const int nch = TT / RCH;
    for (int c = 0; c < nch; ++c) {
        #pragma unroll
        for (int s = 0; s < RCH; ++s) {
            const int p = s & 1;
            if (s == 0 && tid < 256 && c + 1 < nch) {
                const unsigned int* xn = xpw + (size_t)(c + 1) * RCH * 128 + t2;
                #pragma unroll
                for (int s2 = 0; s2 < RCH; ++s2) xpnxt[s2] = xn[(size_t)s2 * 128];
            }
            // --- phase 1: both batches' k-slice dots (8 independent chains) ---
            const uint4* hbA = (const uint4*)&hbits[0][p][q * 16];
            const uint4* hbB = (const uint4*)&hbits[1][p][q * 16];
            uint4 A0 = hbA[0], A1 = hbA[1], A2 = hbA[2], A3 = hbA[3];
            uint4 B0 = hbB[0], B1 = hbB[1], B2 = hbB[2], B3 = hbB[3];
            f16x2 hA[16] = {
                u2h(A0.x), u2h(A0.y), u2h(A0.z), u2h(A0.w),
                u2h(A1.x), u2h(A1.y), u2h(A1.z), u2h(A1.w),
                u2h(A2.x), u2h(A2.y), u2h(A2.z), u2h(A2.w),
                u2h(A3.x), u2h(A3.y), u2h(A3.z), u2h(A3.w)};
            f16x2 hB[16] = {
                u2h(B0.x), u2h(B0.y), u2h(B0.z), u2h(B0.w),
                u2h(B1.x), u2h(B1.y), u2h(B1.z), u2h(B1.w),
                u2h(B2.x), u2h(B2.y), u2h(B2.z), u2h(B2.w),
                u2h(B3.x), u2h(B3.y), u2h(B3.z), u2h(B3.w)};
            float a0 = 0.f, a1 = 0.f, a2 = 0.f, a3 = 0.f;
            float b0a = 0.f, b1a = 0.f, b2a = 0.f, b3a = 0.f;
            #pragma unroll
            for (int cc = 0; cc < 16; ++cc) {
                a0 = fdot2(w2[0][cc], hA[cc], a0);
                a1 = fdot2(w2[1][cc], hA[cc], a1);
                a2 = fdot2(w2[2][cc], hA[cc], a2);
                a3 = fdot2(w2[3][cc], hA[cc], a3);
                b0a = fdot2(w2[0][cc], hB[cc], b0a);
                b1a = fdot2(w2[1][cc], hB[cc], b1a);
                b2a = fdot2(w2[2][cc], hB[cc], b2a);
                b3a = fdot2(w2[3][cc], hB[cc], b3a);
            }
            *(float4*)(&ps[0][q][4 * l]) = make_float4(a0, a1, a2, a3);
            *(float4*)(&ps[1][q][4 * l]) = make_float4(b0a, b1a, b2a, b3a);
            step_barrier();

            // --- phase 2: batch A on waves 0-1, batch B on waves 2-3 ---
            if (tid < 256) {
                float sx = 0.f, sy = 0.f;
                #pragma unroll
                for (int qq = 0; qq < 8; ++qq) {
                    float2 v = *(const float2*)&ps[bb][qq][2 * t2];
                    sx += v.x; sy += v.y;
                }
                f16x2 xv = u2h(xpcur[s]);
                float h0 = tanh_fast(sx + (float)xv.x);
                float h1 = tanh_fast(sy + (float)xv.y);
                unsigned int hb2 = packf16(h0, h1);
                hbits[bb][p ^ 1][t2] = hb2;
                hst[s] = hb2;
            }
            step_barrier();
        }
        if (tid < 256) {
            unsigned int* hwc = hw + (size_t)c * RCH * 128 + t2;
            #pragma unroll
            for (int s = 0; s < RCH; ++s) hwc[(size_t)s * 128] = hst[s];
            #pragma unroll
            for (int s = 0; s < RCH; ++s) xpcur[s] = xpnxt[s];
        }
    }
}

// ---------------------------------------------------------------------------
extern "C" void kernel_launch(void* const* d_in, const int* in_sizes, int n_in,
                              void* d_out, int out_size, void* d_ws, size_t ws_size,
                              hipStream_t stream) {
    const float* x     = (const float*)d_in[0];   // [B][T][I]
    const float* W_in  = (const float*)d_in[1];   // [H][I]
    const float* b_in  = (const float*)d_in[2];   // [H]
    const float* W_out = (const float*)d_in[3];   // [O][H]
    const float* b_out = (const float*)d_in[4];   // [O]
    const float* u_raw = (const float*)d_in[5];   // [M][H]
    const float* sig   = (const float*)d_in[6];   // [H]
    const float* v_raw = (const float*)d_in[7];   // [M][H]
    float* out = (float*)d_out;                   // [B][T][O]

    char* ws = (char*)d_ws;
    size_t off = 0;
    auto alloc = [&](size_t bytes) -> void* {
        void* p = (void*)(ws + off);
        off += (bytes + 255) & ~((size_t)255);
        return p;
    };
    float* u_eff  = (float*)alloc((size_t)HH * HH * 4);
    float* v_eff  = (float*)alloc((size_t)HH * HH * 4);
    float* beta_u = (float*)alloc((size_t)HH * 4);
    float* beta_v = (float*)alloc((size_t)HH * 4);
    float* Ucol   = (float*)alloc((size_t)HH * HH * 4);
    float* Vrow   = (float*)alloc((size_t)HH * HH * 4);
    float* Wm     = (float*)alloc((size_t)HH * HH * 4);
    __half* xpbuf = (__half*)alloc((size_t)BB * TT * HH * 2);
    __half* hall  = (__half*)alloc((size_t)BB * TT * HH * 2);
    (void)ws_size; (void)in_sizes; (void)n_in; (void)out_size;

    prep_kernel<<<2 * HH, 64, 0, stream>>>(u_raw, v_raw, u_eff, v_eff, beta_u, beta_v);
    hh_kernel<<<(2 * HH) / 4, 256, 0, stream>>>(u_eff, v_eff, beta_u, beta_v, Ucol, Vrow);
    w_kernel<<<HH, HH, 0, stream>>>(Ucol, Vrow, sig, Wm);
    gemm_mfma<float, __half>
        <<<dim3((BB * TT) / 128, HH / 64), 256, 0, stream>>>(x, W_in, b_in, xpbuf, BB * TT, HH, II);
    recur_kernel<<<BB / 2, 512, 0, stream>>>(Wm, xpbuf, hall);
    gemm_mfma<__half, float>
        <<<dim3((BB * TT) / 128, OO / 64), 256, 0, stream>>>(hall, W_out, b_out, out, BB * TT, OO, HH);
}

// Round 3
// 1572.179 us; speedup vs baseline: 1.3474x; 1.3474x over previous
//
#include <hip/hip_runtime.h>
#include <hip/hip_bf16.h>
#include <hip/hip_fp16.h>

// SVD-RNN: W = U diag(s) V from Householder chains; h_t = tanh(xp_t + W h_{t-1});
// out_t = h_t W_out^T + b_out.
#define BB 64
#define TT 2048
#define II 128
#define HH 256
#define OO 128
#define RCH 8                      // recurrence chunk length (global I/O batching)

typedef _Float16 f16x2 __attribute__((ext_vector_type(2)));
typedef _Float16 f16x8 __attribute__((ext_vector_type(8)));
typedef float f32x4 __attribute__((ext_vector_type(4)));

#if __has_builtin(__builtin_amdgcn_fdot2)
__device__ __forceinline__ float fdot2(f16x2 a, f16x2 b, float c) {
    return __builtin_amdgcn_fdot2(a, b, c, false);
}
#else
__device__ __forceinline__ float fdot2(f16x2 a, f16x2 b, float c) {
    return fmaf((float)a.x, (float)b.x, fmaf((float)a.y, (float)b.y, c));
}
#endif

__device__ __forceinline__ f16x2 u2h(unsigned int u) { return __builtin_bit_cast(f16x2, u); }
__device__ __forceinline__ unsigned int packf16(float a, float b) {
    return __builtin_bit_cast(unsigned int, f16x2{(_Float16)a, (_Float16)b});
}

__device__ __forceinline__ float tanh_fast(float x) {
    float xc = fminf(fmaxf(x, -9.0f), 9.0f);
    float e = __expf(2.0f * xc);
    return (e - 1.0f) * __fdividef(1.0f, e + 1.0f);
}

// lgkm-only workgroup barrier: orders LDS writes/reads across waves WITHOUT
// draining vmcnt, so chunked global prefetch/stores stay in flight across
// steps (stock __syncthreads emits s_waitcnt vmcnt(0) expcnt(0) lgkmcnt(0)
// which would expose the xp-prefetch HBM latency once per chunk).
__device__ __forceinline__ void step_barrier() {
    __builtin_amdgcn_sched_barrier(0);
    asm volatile("s_waitcnt lgkmcnt(0)" ::: "memory");
    __builtin_amdgcn_s_barrier();
    __builtin_amdgcn_sched_barrier(0);
}

// ---------------------------------------------------------------------------
// Kernel 1: masked+flipped Householder vectors and betas.
// ---------------------------------------------------------------------------
__global__ __launch_bounds__(64) void prep_kernel(
    const float* __restrict__ u_raw, const float* __restrict__ v_raw,
    float* __restrict__ u_eff, float* __restrict__ v_eff,
    float* __restrict__ beta_u, float* __restrict__ beta_v)
{
    const int row = blockIdx.x;
    const int lane = threadIdx.x;
    const bool isU = row < HH;
    const int i = isU ? row : row - HH;
    const float* src = isU ? (u_raw + (size_t)i * HH) : (v_raw + (size_t)(HH - 1 - i) * HH);
    float* dst = (isU ? u_eff : v_eff) + (size_t)i * HH;
    const int lo = isU ? (HH - 1 - i) : i;
    float ss = 0.0f;
    for (int c = lane; c < HH; c += 64) {
        float vv = (c >= lo) ? src[HH - 1 - c] : 0.0f;
        dst[c] = vv;
        ss += vv * vv;
    }
    for (int m = 1; m < 64; m <<= 1) ss += __shfl_xor(ss, m, 64);
    if (lane == 0) (isU ? beta_u : beta_v)[i] = 2.0f / ss;
}

// ---------------------------------------------------------------------------
// Kernel 2: Householder chain per column.
// ---------------------------------------------------------------------------
__global__ __launch_bounds__(256) void hh_kernel(
    const float* __restrict__ u_eff, const float* __restrict__ v_eff,
    const float* __restrict__ beta_u, const float* __restrict__ beta_v,
    float* __restrict__ Ucol, float* __restrict__ Vrow)
{
    const int wid = blockIdx.x * 4 + (threadIdx.x >> 6);
    const int lane = threadIdx.x & 63;
    const bool isU = wid < HH;
    const int j = isU ? wid : wid - HH;
    const float* eff = isU ? u_eff : v_eff;
    const float* beta = isU ? beta_u : beta_v;

    float cr0 = (j == 4 * lane + 0) ? 1.0f : 0.0f;
    float cr1 = (j == 4 * lane + 1) ? 1.0f : 0.0f;
    float cr2 = (j == 4 * lane + 2) ? 1.0f : 0.0f;
    float cr3 = (j == 4 * lane + 3) ? 1.0f : 0.0f;

    const int i0 = isU ? (HH - 1 - j) : 0;
    for (int i = i0; i < HH; ++i) {
        const float4 v4 = *(const float4*)(eff + (size_t)i * HH + lane * 4);
        float d = v4.x * cr0 + v4.y * cr1 + v4.z * cr2 + v4.w * cr3;
        for (int m = 1; m < 64; m <<= 1) d += __shfl_xor(d, m, 64);
        const float t = beta[i] * d;
        cr0 = fmaf(-t, v4.x, cr0);
        cr1 = fmaf(-t, v4.y, cr1);
        cr2 = fmaf(-t, v4.z, cr2);
        cr3 = fmaf(-t, v4.w, cr3);
    }
    if (isU) {
        *(float4*)(Ucol + (size_t)j * HH + lane * 4) = make_float4(cr0, cr1, cr2, cr3);
    } else {
        Vrow[(size_t)(4 * lane + 0) * HH + j] = cr0;
        Vrow[(size_t)(4 * lane + 1) * HH + j] = cr1;
        Vrow[(size_t)(4 * lane + 2) * HH + j] = cr2;
        Vrow[(size_t)(4 * lane + 3) * HH + j] = cr3;
    }
}

// ---------------------------------------------------------------------------
// Kernel 3: W[r][c] = sum_k Ucol[k][r] * sig[k] * Vrow[k][c]
// ---------------------------------------------------------------------------
__global__ __launch_bounds__(256) void w_kernel(
    const float* __restrict__ Ucol, const float* __restrict__ Vrow,
    const float* __restrict__ sig, float* __restrict__ Wm)
{
    const int r = blockIdx.x;
    const int c = threadIdx.x;
    float acc = 0.0f;
    #pragma unroll 4
    for (int k = 0; k < HH; ++k) {
        acc = fmaf(Ucol[(size_t)k * HH + r] * sig[k], Vrow[(size_t)k * HH + c], acc);
    }
    Wm[(size_t)r * HH + c] = acc;
}

// ---------------------------------------------------------------------------
// MFMA tiled GEMM with bias: C[M][N] = A[M][K] * B[N][K]^T + bias[N].
// BM=128, BN=64, BK=32; 256 threads = 4 waves, each wave a 64x32 quadrant
// (4 m-tiles x 2 n-tiles of 16x16, mfma_f32_16x16x32_f16).
// ---------------------------------------------------------------------------
__device__ __forceinline__ void stage16(_Float16* dst, const float* src) {
    #pragma unroll
    for (int i = 0; i < 4; ++i) {
        float4 f = ((const float4*)src)[i];
        ((f16x2*)dst)[2 * i + 0] = f16x2{(_Float16)f.x, (_Float16)f.y};
        ((f16x2*)dst)[2 * i + 1] = f16x2{(_Float16)f.z, (_Float16)f.w};
    }
}
__device__ __forceinline__ void stage16(_Float16* dst, const __half* src) {
    ((uint4*)dst)[0] = ((const uint4*)src)[0];
    ((uint4*)dst)[1] = ((const uint4*)src)[1];
}
__device__ __forceinline__ void storeC(float* p, float v) { *p = v; }
__device__ __forceinline__ void storeC(__half* p, float v) { *p = __float2half_rn(v); }

template <typename AT, typename OT>
__global__ __launch_bounds__(256) void gemm_mfma(
    const AT* __restrict__ A, const float* __restrict__ Bm,
    const float* __restrict__ bias, OT* __restrict__ C,
    int M, int N, int K)
{
    __shared__ _Float16 As[128][40];
    __shared__ _Float16 Bs[64][40];
    const int tid = threadIdx.x;
    const int m0 = blockIdx.x * 128;
    const int n0 = blockIdx.y * 64;
    const int lane = tid & 63;
    const int w = tid >> 6;
    const int lo = lane & 15;
    const int qd = lane >> 4;
    const int mh = w >> 1;               // m-half (64 rows)
    const int nh = w & 1;                // n-half (32 cols)
    const int srow = tid >> 1;           // staging row 0..127
    const int shalf = tid & 1;           // 16-f16 half of the 32-k row

    f32x4 acc[4][2] = {};
    for (int k0 = 0; k0 < K; k0 += 32) {
        stage16(&As[srow][shalf * 16], A + (size_t)(m0 + srow) * K + k0 + shalf * 16);
        if (tid < 128)
            stage16(&Bs[srow][shalf * 16], Bm + (size_t)(n0 + srow) * K + k0 + shalf * 16);
        __syncthreads();
        f16x8 af[4], bf[2];
        #pragma unroll
        for (int mt = 0; mt < 4; ++mt)
            af[mt] = *(const f16x8*)&As[64 * mh + 16 * mt + lo][qd * 8];
        #pragma unroll
        for (int nt = 0; nt < 2; ++nt)
            bf[nt] = *(const f16x8*)&Bs[32 * nh + 16 * nt + lo][qd * 8];
        #pragma unroll
        for (int mt = 0; mt < 4; ++mt)
            #pragma unroll
            for (int nt = 0; nt < 2; ++nt)
                acc[mt][nt] = __builtin_amdgcn_mfma_f32_16x16x32_f16(
                    af[mt], bf[nt], acc[mt][nt], 0, 0, 0);
        __syncthreads();
    }
    #pragma unroll
    for (int nt = 0; nt < 2; ++nt) {
        const int n = n0 + 32 * nh + 16 * nt + lo;
        const float bv = bias[n];
        #pragma unroll
        for (int mt = 0; mt < 4; ++mt) {
            const int m = m0 + 64 * mh + 16 * mt + 4 * qd;
            #pragma unroll
            for (int r = 0; r < 4; ++r)
                storeC(C + (size_t)(m + r) * N + n, acc[mt][nt][r] + bv);
        }
    }
}

// ---------------------------------------------------------------------------
// Kernel 5: recurrence — ONE barrier/step, wave-local h, redundant reduce.
// 64 WGs x 512 threads (8 waves), 1 batch/WG (all 64 CUs of the batch dim).
// Wave q owns k-slice cols [32q,32q+32); lane l owns rows 4l..4l+3 (W frag
// 64 VGPRs as f16x2). KEY CHANGES vs the 1183us 2-barrier shape:
//  * h lives in REGISTERS: packed pair per even lane; dot reads it via
//    v_readlane (SGPR broadcast feeding v_dot2 directly) — removes all 32
//    h-broadcast LDS reads AND the h LDS buffer.
//  * phase 2 is done REDUNDANTLY by every wave for the slice it needs next
//    step (elements [32q,32q+32)), so the ps->h handoff is wave-local:
//    only ONE barrier per step (between ps write and ps read).
//  * ps double-buffered (16 KB): phase1(s+1) writes ps[p^1] while stragglers
//    may still read ps[p]; reuse of ps[p] is ordered by barrier(s+1) since
//    phase2(s) precedes phase1(s+1) in every wave's program order.
//  * barrier is lgkm-only: chunked xp prefetch / hall stores (vmcnt) stay
//    in flight across steps.
// R1 lesson (row-split): avoid per-lane h read amplification — readlane
// broadcast costs 16 VALU/step, not 16 LDS ops.
// R2 lesson: extra work at the SAME barriers doesn't pipeline; removing a
// barrier + a handoff does.
// ---------------------------------------------------------------------------
__global__ __launch_bounds__(512) void recur_kernel(
    const float* __restrict__ Wm,              // [256][256] f32 row-major
    const __half* __restrict__ xp,             // [B][T][256] f16
    __half* __restrict__ hall)                 // [B][T][256] f16
{
    const int b = blockIdx.x;
    const int tid = threadIdx.x;
    const int l = tid & 63;
    const int q = tid >> 6;        // wave 0..7
    const int lr = l & 31;         // element offset within wave's slice
    const int hh = l >> 5;         // qq-half selector for phase-2 split

    __shared__ float ps[2][8][HH];             // double-buffered partials, 16 KB

    // W fragment: rows 4l..4l+3, cols q*32..q*32+32, as f16 pairs (64 VGPRs).
    f16x2 w2[4][16];
    #pragma unroll
    for (int r = 0; r < 4; ++r) {
        const float* Wp = Wm + (size_t)(4 * l + r) * HH + q * 32;
        #pragma unroll
        for (int c4 = 0; c4 < 8; ++c4) {
            float4 f = *(const float4*)(Wp + c4 * 4);
            w2[r][c4 * 2 + 0] = f16x2{(_Float16)f.x, (_Float16)f.y};
            w2[r][c4 * 2 + 1] = f16x2{(_Float16)f.z, (_Float16)f.w};
        }
    }

    const int e = 32 * q + lr;                 // h element this lane reduces
    const _Float16* xph = (const _Float16*)xp + (size_t)b * TT * HH + e;
    unsigned int* hw = (unsigned int*)(hall + (size_t)b * TT * HH) + (e >> 1);
    const bool st = (l < 32) && !(l & 1);      // storing lanes (one per pair)

    _Float16 xpc[RCH], xpn[RCH];
    unsigned int hst[RCH];
    #pragma unroll
    for (int s = 0; s < RCH; ++s) xpc[s] = xph[(size_t)s * HH];

    unsigned int v = 0u;   // packed f16x2 h pair; valid at even lanes (h=0 init)
    int p = 0;
    const int nch = TT / RCH;
    for (int c = 0; c < nch; ++c) {
        if (c + 1 < nch) {
            const _Float16* xn = xph + (size_t)(c + 1) * RCH * HH;
            #pragma unroll
            for (int s = 0; s < RCH; ++s) xpn[s] = xn[(size_t)s * HH];
        }
        #pragma unroll
        for (int s = 0; s < RCH; ++s) {
            // --- phase 1: k-slice dot; h pairs broadcast via readlane ---
            float a0 = 0.f, a1 = 0.f, a2 = 0.f, a3 = 0.f;
            #pragma unroll
            for (int j = 0; j < 16; ++j) {
                f16x2 hj = u2h((unsigned int)__builtin_amdgcn_readlane((int)v, 2 * j));
                a0 = fdot2(w2[0][j], hj, a0);
                a1 = fdot2(w2[1][j], hj, a1);
                a2 = fdot2(w2[2][j], hj, a2);
                a3 = fdot2(w2[3][j], hj, a3);
            }
            *(float4*)&ps[p][q][4 * l] = make_float4(a0, a1, a2, a3);
            step_barrier();

            // --- phase 2 (every wave, its own slice): element e ---
            float s4 = (ps[p][4 * hh + 0][e] + ps[p][4 * hh + 1][e])
                     + (ps[p][4 * hh + 2][e] + ps[p][4 * hh + 3][e]);
            float tot = s4 + __shfl_xor(s4, 32, 64);       // combine qq halves
            float hv = tanh_fast(tot + (float)xpc[s]);
            float ho = __shfl_xor(hv, 1, 64);              // pair partner
            v = packf16(hv, ho);                           // valid at even lanes
            hst[s] = v;
            p ^= 1;
        }
        if (st) {
            unsigned int* hwc = hw + (size_t)c * RCH * 128;
            #pragma unroll
            for (int s2 = 0; s2 < RCH; ++s2) hwc[(size_t)s2 * 128] = hst[s2];
        }
        #pragma unroll
        for (int s2 = 0; s2 < RCH; ++s2) xpc[s2] = xpn[s2];
    }
}

// ---------------------------------------------------------------------------
extern "C" void kernel_launch(void* const* d_in, const int* in_sizes, int n_in,
                              void* d_out, int out_size, void* d_ws, size_t ws_size,
                              hipStream_t stream) {
    const float* x     = (const float*)d_in[0];   // [B][T][I]
    const float* W_in  = (const float*)d_in[1];   // [H][I]
    const float* b_in  = (const float*)d_in[2];   // [H]
    const float* W_out = (const float*)d_in[3];   // [O][H]
    const float* b_out = (const float*)d_in[4];   // [O]
    const float* u_raw = (const float*)d_in[5];   // [M][H]
    const float* sig   = (const float*)d_in[6];   // [H]
    const float* v_raw = (const float*)d_in[7];   // [M][H]
    float* out = (float*)d_out;                   // [B][T][O]

    char* ws = (char*)d_ws;
    size_t off = 0;
    auto alloc = [&](size_t bytes) -> void* {
        void* p = (void*)(ws + off);
        off += (bytes + 255) & ~((size_t)255);
        return p;
    };
    float* u_eff  = (float*)alloc((size_t)HH * HH * 4);
    float* v_eff  = (float*)alloc((size_t)HH * HH * 4);
    float* beta_u = (float*)alloc((size_t)HH * 4);
    float* beta_v = (float*)alloc((size_t)HH * 4);
    float* Ucol   = (float*)alloc((size_t)HH * HH * 4);
    float* Vrow   = (float*)alloc((size_t)HH * HH * 4);
    float* Wm     = (float*)alloc((size_t)HH * HH * 4);
    __half* xpbuf = (__half*)alloc((size_t)BB * TT * HH * 2);
    __half* hall  = (__half*)alloc((size_t)BB * TT * HH * 2);
    (void)ws_size; (void)in_sizes; (void)n_in; (void)out_size;

    prep_kernel<<<2 * HH, 64, 0, stream>>>(u_raw, v_raw, u_eff, v_eff, beta_u, beta_v);
    hh_kernel<<<(2 * HH) / 4, 256, 0, stream>>>(u_eff, v_eff, beta_u, beta_v, Ucol, Vrow);
    w_kernel<<<HH, HH, 0, stream>>>(Ucol, Vrow, sig, Wm);
    gemm_mfma<float, __half>
        <<<dim3((BB * TT) / 128, HH / 64), 256, 0, stream>>>(x, W_in, b_in, xpbuf, BB * TT, HH, II);
    recur_kernel<<<BB, 512, 0, stream>>>(Wm, xpbuf, hall);
    gemm_mfma<__half, float>
        <<<dim3((BB * TT) / 128, OO / 64), 256, 0, stream>>>(hall, W_out, b_out, out, BB * TT, OO, HH);
}

// Round 11
// 1384.138 us; speedup vs baseline: 1.5304x; 1.1359x over previous
//
#include <hip/hip_runtime.h>
#include <hip/hip_bf16.h>
#include <hip/hip_fp16.h>

// SVD-RNN: W = U diag(s) V from Householder chains; h_t = tanh(xp_t + W h_{t-1});
// out_t = h_t W_out^T + b_out.
#define BB 64
#define TT 2048
#define II 128
#define HH 256
#define OO 128
#define RCH 8                      // recurrence chunk length (global I/O batching)

typedef _Float16 f16x2 __attribute__((ext_vector_type(2)));
typedef _Float16 f16x8 __attribute__((ext_vector_type(8)));
typedef float f32x4 __attribute__((ext_vector_type(4)));

#if __has_builtin(__builtin_amdgcn_fdot2)
__device__ __forceinline__ float fdot2(f16x2 a, f16x2 b, float c) {
    return __builtin_amdgcn_fdot2(a, b, c, false);
}
#else
__device__ __forceinline__ float fdot2(f16x2 a, f16x2 b, float c) {
    return fmaf((float)a.x, (float)b.x, fmaf((float)a.y, (float)b.y, c));
}
#endif

__device__ __forceinline__ f16x2 u2h(unsigned int u) { return __builtin_bit_cast(f16x2, u); }
__device__ __forceinline__ unsigned int packf16(float a, float b) {
    return __builtin_bit_cast(unsigned int, f16x2{(_Float16)a, (_Float16)b});
}

__device__ __forceinline__ float tanh_fast(float x) {
    float xc = fminf(fmaxf(x, -9.0f), 9.0f);
    float e = __expf(2.0f * xc);
    return (e - 1.0f) * __fdividef(1.0f, e + 1.0f);
}

// lgkm-only workgroup barrier: orders LDS writes/reads across waves WITHOUT
// draining vmcnt, so chunked global prefetch/stores stay in flight across
// steps (stock __syncthreads emits s_waitcnt vmcnt(0) expcnt(0) lgkmcnt(0)
// which would expose the xp-prefetch HBM latency once per chunk).
__device__ __forceinline__ void step_barrier() {
    __builtin_amdgcn_sched_barrier(0);
    asm volatile("s_waitcnt lgkmcnt(0)" ::: "memory");
    __builtin_amdgcn_s_barrier();
    __builtin_amdgcn_sched_barrier(0);
}

// ---------------------------------------------------------------------------
// Kernel 1: masked+flipped Householder vectors and betas.
// ---------------------------------------------------------------------------
__global__ __launch_bounds__(64) void prep_kernel(
    const float* __restrict__ u_raw, const float* __restrict__ v_raw,
    float* __restrict__ u_eff, float* __restrict__ v_eff,
    float* __restrict__ beta_u, float* __restrict__ beta_v)
{
    const int row = blockIdx.x;
    const int lane = threadIdx.x;
    const bool isU = row < HH;
    const int i = isU ? row : row - HH;
    const float* src = isU ? (u_raw + (size_t)i * HH) : (v_raw + (size_t)(HH - 1 - i) * HH);
    float* dst = (isU ? u_eff : v_eff) + (size_t)i * HH;
    const int lo = isU ? (HH - 1 - i) : i;
    float ss = 0.0f;
    for (int c = lane; c < HH; c += 64) {
        float vv = (c >= lo) ? src[HH - 1 - c] : 0.0f;
        dst[c] = vv;
        ss += vv * vv;
    }
    for (int m = 1; m < 64; m <<= 1) ss += __shfl_xor(ss, m, 64);
    if (lane == 0) (isU ? beta_u : beta_v)[i] = 2.0f / ss;
}

// ---------------------------------------------------------------------------
// Kernel 2: Householder chain per column.
// ---------------------------------------------------------------------------
__global__ __launch_bounds__(256) void hh_kernel(
    const float* __restrict__ u_eff, const float* __restrict__ v_eff,
    const float* __restrict__ beta_u, const float* __restrict__ beta_v,
    float* __restrict__ Ucol, float* __restrict__ Vrow)
{
    const int wid = blockIdx.x * 4 + (threadIdx.x >> 6);
    const int lane = threadIdx.x & 63;
    const bool isU = wid < HH;
    const int j = isU ? wid : wid - HH;
    const float* eff = isU ? u_eff : v_eff;
    const float* beta = isU ? beta_u : beta_v;

    float cr0 = (j == 4 * lane + 0) ? 1.0f : 0.0f;
    float cr1 = (j == 4 * lane + 1) ? 1.0f : 0.0f;
    float cr2 = (j == 4 * lane + 2) ? 1.0f : 0.0f;
    float cr3 = (j == 4 * lane + 3) ? 1.0f : 0.0f;

    const int i0 = isU ? (HH - 1 - j) : 0;
    for (int i = i0; i < HH; ++i) {
        const float4 v4 = *(const float4*)(eff + (size_t)i * HH + lane * 4);
        float d = v4.x * cr0 + v4.y * cr1 + v4.z * cr2 + v4.w * cr3;
        for (int m = 1; m < 64; m <<= 1) d += __shfl_xor(d, m, 64);
        const float t = beta[i] * d;
        cr0 = fmaf(-t, v4.x, cr0);
        cr1 = fmaf(-t, v4.y, cr1);
        cr2 = fmaf(-t, v4.z, cr2);
        cr3 = fmaf(-t, v4.w, cr3);
    }
    if (isU) {
        *(float4*)(Ucol + (size_t)j * HH + lane * 4) = make_float4(cr0, cr1, cr2, cr3);
    } else {
        Vrow[(size_t)(4 * lane + 0) * HH + j] = cr0;
        Vrow[(size_t)(4 * lane + 1) * HH + j] = cr1;
        Vrow[(size_t)(4 * lane + 2) * HH + j] = cr2;
        Vrow[(size_t)(4 * lane + 3) * HH + j] = cr3;
    }
}

// ---------------------------------------------------------------------------
// Kernel 3: W[r][c] = sum_k Ucol[k][r] * sig[k] * Vrow[k][c]
// ---------------------------------------------------------------------------
__global__ __launch_bounds__(256) void w_kernel(
    const float* __restrict__ Ucol, const float* __restrict__ Vrow,
    const float* __restrict__ sig, float* __restrict__ Wm)
{
    const int r = blockIdx.x;
    const int c = threadIdx.x;
    float acc = 0.0f;
    #pragma unroll 4
    for (int k = 0; k < HH; ++k) {
        acc = fmaf(Ucol[(size_t)k * HH + r] * sig[k], Vrow[(size_t)k * HH + c], acc);
    }
    Wm[(size_t)r * HH + c] = acc;
}

// ---------------------------------------------------------------------------
// MFMA tiled GEMM with bias: C[M][N] = A[M][K] * B[N][K]^T + bias[N].
// BM=128, BN=64, BK=32; 256 threads = 4 waves, each wave a 64x32 quadrant
// (4 m-tiles x 2 n-tiles of 16x16, mfma_f32_16x16x32_f16).
// ---------------------------------------------------------------------------
__device__ __forceinline__ void stage16(_Float16* dst, const float* src) {
    #pragma unroll
    for (int i = 0; i < 4; ++i) {
        float4 f = ((const float4*)src)[i];
        ((f16x2*)dst)[2 * i + 0] = f16x2{(_Float16)f.x, (_Float16)f.y};
        ((f16x2*)dst)[2 * i + 1] = f16x2{(_Float16)f.z, (_Float16)f.w};
    }
}
__device__ __forceinline__ void stage16(_Float16* dst, const __half* src) {
    ((uint4*)dst)[0] = ((const uint4*)src)[0];
    ((uint4*)dst)[1] = ((const uint4*)src)[1];
}
__device__ __forceinline__ void storeC(float* p, float v) { *p = v; }
__device__ __forceinline__ void storeC(__half* p, float v) { *p = __float2half_rn(v); }

template <typename AT, typename OT>
__global__ __launch_bounds__(256) void gemm_mfma(
    const AT* __restrict__ A, const float* __restrict__ Bm,
    const float* __restrict__ bias, OT* __restrict__ C,
    int M, int N, int K)
{
    __shared__ _Float16 As[128][40];
    __shared__ _Float16 Bs[64][40];
    const int tid = threadIdx.x;
    const int m0 = blockIdx.x * 128;
    const int n0 = blockIdx.y * 64;
    const int lane = tid & 63;
    const int w = tid >> 6;
    const int lo = lane & 15;
    const int qd = lane >> 4;
    const int mh = w >> 1;               // m-half (64 rows)
    const int nh = w & 1;                // n-half (32 cols)
    const int srow = tid >> 1;           // staging row 0..127
    const int shalf = tid & 1;           // 16-f16 half of the 32-k row

    f32x4 acc[4][2] = {};
    for (int k0 = 0; k0 < K; k0 += 32) {
        stage16(&As[srow][shalf * 16], A + (size_t)(m0 + srow) * K + k0 + shalf * 16);
        if (tid < 128)
            stage16(&Bs[srow][shalf * 16], Bm + (size_t)(n0 + srow) * K + k0 + shalf * 16);
        __syncthreads();
        f16x8 af[4], bf[2];
        #pragma unroll
        for (int mt = 0; mt < 4; ++mt)
            af[mt] = *(const f16x8*)&As[64 * mh + 16 * mt + lo][qd * 8];
        #pragma unroll
        for (int nt = 0; nt < 2; ++nt)
            bf[nt] = *(const f16x8*)&Bs[32 * nh + 16 * nt + lo][qd * 8];
        #pragma unroll
        for (int mt = 0; mt < 4; ++mt)
            #pragma unroll
            for (int nt = 0; nt < 2; ++nt)
                acc[mt][nt] = __builtin_amdgcn_mfma_f32_16x16x32_f16(
                    af[mt], bf[nt], acc[mt][nt], 0, 0, 0);
        __syncthreads();
    }
    #pragma unroll
    for (int nt = 0; nt < 2; ++nt) {
        const int n = n0 + 32 * nh + 16 * nt + lo;
        const float bv = bias[n];
        #pragma unroll
        for (int mt = 0; mt < 4; ++mt) {
            const int m = m0 + 64 * mh + 16 * mt + 4 * qd;
            #pragma unroll
            for (int r = 0; r < 4; ++r)
                storeC(C + (size_t)(m + r) * N + n, acc[mt][nt][r] + bv);
        }
    }
}

// ---------------------------------------------------------------------------
// Kernel 5: recurrence — 4 WAVES/WG, k-slice 64/wave over ALL rows,
// wave-local h. 64 WGs x 256 threads.
// R9 post-mortem: absmax 0.867 was a single operand typo in the unrolled
// dot (the 4g+2 term of row 3 used p3 instead of p2) — fixed here. The
// structure itself re-verified:
//  * wave q covers k-slice [64q,64q+64) for ALL 256 rows: lane l owns rows
//    4l..4l+3 (W frag 4x32 f16x2 = 128 VGPRs). Union of fragments spans
//    all rows x all k-slices (R8 lesson).
//  * phase 1: 8 uniform b128 reads of hx slice [64q,64q+64) + 128 fdot2 +
//    one b128 ps write.  ONE lgkm-only barrier.
//  * phase 2: thread t reduces element e=t: 4 x b32 ps reads (stride 1KB,
//    conflict-free) + 3 adds + tanh + b16 write to hx[t].
//  * WAVE-LOCAL h: wave q's threads are t in [64q,64q+64) -> they write
//    exactly the hx slice wave q's next dot reads. In-wave DS ordering
//    suffices (no second barrier, no broadcast buffer, no double-buffer).
//  * ps double-buffered (8 KB): reuse of ps[p] at step s+2 ordered by
//    barrier(s+1)'s lgkmcnt(0) drain (argument proven since R3).
//  * per-SIMD issue/step: 8 b128 + 128 dot2 + 1 b128w + ~21 phase2 ~= 166
//    instrs ~= 330 cy (vs ~900 measured in R3, ~430 in the 1183us baseline).
// R1: no per-lane h read amplification. R2: no extra work at same barriers.
// R3: no readlane/redundant phase2. R8: verify fragment coverage. R9:
// verify unrolled operand pairings (w2[r][4g+j] <-> hb[g].{x,y,z,w}[j]).
// ---------------------------------------------------------------------------
__global__ __launch_bounds__(256, 1) void recur_kernel(
    const float* __restrict__ Wm,              // [256][256] f32 row-major
    const __half* __restrict__ xp,             // [B][T][256] f16
    __half* __restrict__ hall)                 // [B][T][256] f16
{
    const int b = blockIdx.x;
    const int tid = threadIdx.x;
    const int l = tid & 63;
    const int q = tid >> 6;        // wave 0..3

    __shared__ float ps[2][4][HH];                    // dbuf partials, 8 KB
    __shared__ __align__(16) _Float16 hx[HH];         // packed h, 512 B

    // W fragment: rows 4l..4l+3, cols [64q,64q+64) as f16 pairs (128 VGPRs).
    f16x2 w2[4][32];
    #pragma unroll
    for (int r = 0; r < 4; ++r) {
        const float* Wp = Wm + (size_t)(4 * l + r) * HH + 64 * q;
        #pragma unroll
        for (int c4 = 0; c4 < 16; ++c4) {
            float4 f = *(const float4*)(Wp + 4 * c4);
            w2[r][2 * c4 + 0] = f16x2{(_Float16)f.x, (_Float16)f.y};
            w2[r][2 * c4 + 1] = f16x2{(_Float16)f.z, (_Float16)f.w};
        }
    }
    if (tid < HH / 2) ((unsigned int*)hx)[tid] = 0u;   // h=0 init
    __syncthreads();

    const _Float16* xpw = (const _Float16*)xp + (size_t)b * TT * HH + tid;
    unsigned short* hw = (unsigned short*)hall + (size_t)b * TT * HH + tid;

    _Float16 xpc[RCH], xpn[RCH], hst[RCH];
    #pragma unroll
    for (int s = 0; s < RCH; ++s) xpc[s] = xpw[(size_t)s * HH];

    const int nch = TT / RCH;
    for (int c = 0; c < nch; ++c) {
        if (c + 1 < nch) {
            const _Float16* xn = xpw + (size_t)(c + 1) * RCH * HH;
            #pragma unroll
            for (int s = 0; s < RCH; ++s) xpn[s] = xn[(size_t)s * HH];
        }
        #pragma unroll
        for (int s = 0; s < RCH; ++s) {
            const int p = s & 1;
            // --- phase 1: k-slice dot over all 4 owned rows ---
            const uint4* hbp = (const uint4*)&hx[64 * q];
            uint4 hb[8];
            #pragma unroll
            for (int g = 0; g < 8; ++g) hb[g] = hbp[g];
            float a0 = 0.f, a1 = 0.f, a2 = 0.f, a3 = 0.f;
            #pragma unroll
            for (int g = 0; g < 8; ++g) {
                f16x2 p0 = u2h(hb[g].x), p1 = u2h(hb[g].y);
                f16x2 p2 = u2h(hb[g].z), p3 = u2h(hb[g].w);
                a0 = fdot2(w2[0][4 * g + 0], p0, a0);
                a1 = fdot2(w2[1][4 * g + 0], p0, a1);
                a2 = fdot2(w2[2][4 * g + 0], p0, a2);
                a3 = fdot2(w2[3][4 * g + 0], p0, a3);
                a0 = fdot2(w2[0][4 * g + 1], p1, a0);
                a1 = fdot2(w2[1][4 * g + 1], p1, a1);
                a2 = fdot2(w2[2][4 * g + 1], p1, a2);
                a3 = fdot2(w2[3][4 * g + 1], p1, a3);
                a0 = fdot2(w2[0][4 * g + 2], p2, a0);
                a1 = fdot2(w2[1][4 * g + 2], p2, a1);
                a2 = fdot2(w2[2][4 * g + 2], p2, a2);
                a3 = fdot2(w2[3][4 * g + 2], p2, a3);   // R9 fix: was p3
                a0 = fdot2(w2[0][4 * g + 3], p3, a0);
                a1 = fdot2(w2[1][4 * g + 3], p3, a1);
                a2 = fdot2(w2[2][4 * g + 3], p3, a2);
                a3 = fdot2(w2[3][4 * g + 3], p3, a3);
            }
            *(float4*)&ps[p][q][4 * l] = make_float4(a0, a1, a2, a3);
            step_barrier();

            // --- phase 2: element e = tid, 4-way reduce + tanh ---
            float sum = (ps[p][0][tid] + ps[p][1][tid])
                      + (ps[p][2][tid] + ps[p][3][tid]);
            float h = tanh_fast(sum + (float)xpc[s]);
            _Float16 hh = (_Float16)h;
            hx[tid] = hh;          // own-wave slice; in-wave DS order
            hst[s] = hh;
        }
        unsigned short* hwc = hw + (size_t)c * RCH * HH;
        #pragma unroll
        for (int s2 = 0; s2 < RCH; ++s2)
            hwc[(size_t)s2 * HH] = __builtin_bit_cast(unsigned short, hst[s2]);
        #pragma unroll
        for (int s2 = 0; s2 < RCH; ++s2) xpc[s2] = xpn[s2];
    }
}

// ---------------------------------------------------------------------------
extern "C" void kernel_launch(void* const* d_in, const int* in_sizes, int n_in,
                              void* d_out, int out_size, void* d_ws, size_t ws_size,
                              hipStream_t stream) {
    const float* x     = (const float*)d_in[0];   // [B][T][I]
    const float* W_in  = (const float*)d_in[1];   // [H][I]
    const float* b_in  = (const float*)d_in[2];   // [H]
    const float* W_out = (const float*)d_in[3];   // [O][H]
    const float* b_out = (const float*)d_in[4];   // [O]
    const float* u_raw = (const float*)d_in[5];   // [M][H]
    const float* sig   = (const float*)d_in[6];   // [H]
    const float* v_raw = (const float*)d_in[7];   // [M][H]
    float* out = (float*)d_out;                   // [B][T][O]

    char* ws = (char*)d_ws;
    size_t off = 0;
    auto alloc = [&](size_t bytes) -> void* {
        void* p = (void*)(ws + off);
        off += (bytes + 255) & ~((size_t)255);
        return p;
    };
    float* u_eff  = (float*)alloc((size_t)HH * HH * 4);
    float* v_eff  = (float*)alloc((size_t)HH * HH * 4);
    float* beta_u = (float*)alloc((size_t)HH * 4);
    float* beta_v = (float*)alloc((size_t)HH * 4);
    float* Ucol   = (float*)alloc((size_t)HH * HH * 4);
    float* Vrow   = (float*)alloc((size_t)HH * HH * 4);
    float* Wm     = (float*)alloc((size_t)HH * HH * 4);
    __half* xpbuf = (__half*)alloc((size_t)BB * TT * HH * 2);
    __half* hall  = (__half*)alloc((size_t)BB * TT * HH * 2);
    (void)ws_size; (void)in_sizes; (void)n_in; (void)out_size;

    prep_kernel<<<2 * HH, 64, 0, stream>>>(u_raw, v_raw, u_eff, v_eff, beta_u, beta_v);
    hh_kernel<<<(2 * HH) / 4, 256, 0, stream>>>(u_eff, v_eff, beta_u, beta_v, Ucol, Vrow);
    w_kernel<<<HH, HH, 0, stream>>>(Ucol, Vrow, sig, Wm);
    gemm_mfma<float, __half>
        <<<dim3((BB * TT) / 128, HH / 64), 256, 0, stream>>>(x, W_in, b_in, xpbuf, BB * TT, HH, II);
    recur_kernel<<<BB, 256, 0, stream>>>(Wm, xpbuf, hall);
    gemm_mfma<__half, float>
        <<<dim3((BB * TT) / 128, OO / 64), 256, 0, stream>>>(hall, W_out, b_out, out, BB * TT, OO, HH);
}